// Round 5
// baseline (689.139 us; speedup 1.0000x reference)
//
#include <hip/hip_runtime.h>
#include <hip/hip_bf16.h>

// B=8, N=4096, D=1024, 3 iterations.
// Algebra: fg = (feat @ W_f) @ Wg_mean^T is never materialized.
//   delta[b,n] = feat[b,n,:] . v_b,  v = t @ W_f^T, t = q @ Wg_mean
//   out[b,:]   = u @ Wg_mean^T,      u = s @ W_f,   s[b,k] = sum_n c[b,n] feat[b,n,k]
// Scratch in __device__ globals. Input dtypes (bf16 vs f32) sniffed at runtime
// per tensor by kdet. OUTPUT IS F32 (reference returns jnp.float32; harness doc:
// d_out is the reference's output dtype -> float*).

using u16 = unsigned short;
using u32 = unsigned int;
using u8  = unsigned char;

#define SELU_L 1.0507009873554805f
#define SELU_A 1.6732632423543772f

__device__ float g_M[1048576];   // Wg mean (fp32)
__device__ float g_q[8192];      // running q state
__device__ float g_tus[24576];   // t | u | s (zeroed each iteration by kzero)
__device__ float g_bst[32768];   // b logits state
__device__ float g_c[32768];     // softmax
__device__ float g_delta[32768];
__device__ float g_outv[8192];
__device__ float g_v[8192];
__device__ int   g_dt[12];       // 0..8: 0=bf16,1=f32 per float input; [9]=mask mode

__device__ __forceinline__ float blo(u32 u){ return __uint_as_float(u << 16); }
__device__ __forceinline__ float bhi(u32 u){ return __uint_as_float(u & 0xffff0000u); }
__device__ __forceinline__ float b2f(u16 u){ return __uint_as_float(((u32)u) << 16); }

__device__ __forceinline__ void unpack8(uint4 x, float* f){
  f[0]=blo(x.x); f[1]=bhi(x.x); f[2]=blo(x.y); f[3]=bhi(x.y);
  f[4]=blo(x.z); f[5]=bhi(x.z); f[6]=blo(x.w); f[7]=bhi(x.w);
}

// scalar load of element i with runtime dtype
__device__ __forceinline__ float ldf(const void* p, size_t i, int dt){
  return dt ? ((const float*)p)[i] : b2f(((const u16*)p)[i]);
}
// 8 consecutive elements starting at idx (idx multiple of 8)
__device__ __forceinline__ void load8(const void* base, size_t idx, int dt, float* f){
  if (dt == 0) {
    uint4 x = *(const uint4*)((const u16*)base + idx);
    unpack8(x, f);
  } else {
    const float* p = (const float*)base + idx;
    float4 a = *(const float4*)p, b = *(const float4*)(p + 4);
    f[0]=a.x; f[1]=a.y; f[2]=a.z; f[3]=a.w; f[4]=b.x; f[5]=b.y; f[6]=b.z; f[7]=b.w;
  }
}

__device__ __forceinline__ float wredsum(float x){
#pragma unroll
  for (int o = 32; o; o >>= 1) x += __shfl_xor(x, o, 64);
  return x;
}

// ---- dtype sniffer: thread t inspects tensor t ------------------------------
__global__ void kdet(const void* p0, const void* p1, const void* p2, const void* p3,
                     const void* p4, const void* p5, const void* p6, const void* p7,
                     const void* p8, const void* p9)
{
  const void* ps[10] = {p0,p1,p2,p3,p4,p5,p6,p7,p8,p9};
  int t = threadIdx.x;
  if (t < 9) {
    const u16* w = (const u16*)ps[t];
    int evenNZ = 0, oddNZ = 0, nz = 0, pass = 0;
    for (int i = 0; i < 128; ++i) {
      u16 x = w[i];
      if (x) {
        ++nz;
        if (i & 1) ++oddNZ; else ++evenNZ;
        int e = (x >> 7) & 0xFF;
        if (e >= 0x70 && e <= 0x8F) ++pass;   // sane exponent for O(1)-scale data
      }
    }
    int dt;
    if (nz == 0)                    dt = 0;   // all-zero tensor: bf16 read is safe
    else if (evenNZ == 0 && oddNZ)  dt = 1;   // f32 signature (e.g. 1.0f pattern)
    else                            dt = (pass * 10 >= nz * 9) ? 0 : 1;
    g_dt[t] = dt;
  } else if (t == 9) {
    // mask wire-format: 0=u8,1=i32,2=bf16,3=f32,4=f16,5=i64
    const u8* mp = (const u8*)ps[9];
    bool f16c=false, isF=false, nz01=false, nzNon4=false, nzM8_4=false, anynz=false;
    for (int i = 0; i < 512; ++i) {
      u8 cb = mp[i];
      if (!cb) continue;
      anynz = true;
      if (cb == 0x3C && (i & 1)) f16c = true;
      if (cb == 0x3F || cb == 0x80) isF = true;
      int m = i & 3;
      if (m == 0 || m == 1) nz01 = true;
      if (m != 0) nzNon4 = true;
      if ((i & 7) == 4) nzM8_4 = true;
    }
    int mode;
    if (f16c)        mode = 4;
    else if (isF)    mode = nz01 ? 2 : 3;
    else if (nzNon4) mode = 0;
    else if (nzM8_4) mode = 1;
    else if (anynz)  mode = 5;
    else             mode = 1;
    g_dt[9] = mode;
  }
}

__global__ void kzero() {
  int i = (blockIdx.x * 256 + threadIdx.x) * 4;
  *(float4*)(g_tus + i) = make_float4(0.f, 0.f, 0.f, 0.f);
}

// ---- prep: M = mean_g Wg (blk<1024) | q0 = query@W_h (blk<1028) | mask (rest)
__global__ void kprep(const void* __restrict__ Wg, const void* __restrict__ Wh,
                      const void* __restrict__ query, const u8* __restrict__ maskp)
{
  int blk = blockIdx.x, tid = threadIdx.x;
  if (blk < 1024) {
    int dtg = g_dt[4];
    int e = blk * 1024 + tid * 4;
    float a0=0.f,a1=0.f,a2=0.f,a3=0.f;
#pragma unroll
    for (int g = 0; g < 4; ++g) {
      size_t o = (size_t)g * 1048576 + e;
      a0 += ldf(Wg, o+0, dtg); a1 += ldf(Wg, o+1, dtg);
      a2 += ldf(Wg, o+2, dtg); a3 += ldf(Wg, o+3, dtg);
    }
    *(float4*)(g_M + e) = make_float4(a0*0.25f, a1*0.25f, a2*0.25f, a3*0.25f);
  } else if (blk < 1028) {
    int dtq = g_dt[0], dth = g_dt[2];
    __shared__ float ql[8192];
    for (int idx = tid; idx < 8192; idx += 256) ql[idx] = ldf(query, idx, dtq);
    __syncthreads();
    int k = (blk - 1024) * 256 + tid;
    float acc[8] = {0,0,0,0,0,0,0,0};
    for (int d = 0; d < 1024; ++d) {
      float w = ldf(Wh, (size_t)d * 1024 + k, dth);
#pragma unroll
      for (int b = 0; b < 8; ++b) acc[b] += ql[(b << 10) + d] * w;
    }
#pragma unroll
    for (int b = 0; b < 8; ++b) g_q[b * 1024 + k] = acc[b];
  } else {
    int mode = g_dt[9];
    int e0 = (blk - 1028) * 1024 + tid * 4;
#pragma unroll
    for (int j = 0; j < 4; ++j) {
      int e = e0 + j;
      bool on;
      if (mode == 0)      on = maskp[e] != 0;
      else if (mode == 1) on = ((const int*)maskp)[e] != 0;
      else if (mode == 2) on = ((const u16*)maskp)[e] != 0;
      else if (mode == 3) on = ((const u32*)maskp)[e] != 0;
      else if (mode == 4) on = ((const u16*)maskp)[e] != 0;
      else                on = ((const unsigned long long*)maskp)[e] != 0ULL;
      g_bst[e] = on ? -1e18f : 0.f;
    }
  }
}

// ---- softmax(bst)->c (blk<8)  |  t = q @ M split-k atomics (blk 8..39) ------
__global__ void ksm(int do_t)
{
  __shared__ float sm[1024];
  int blk = blockIdx.x, tid = threadIdx.x;
  float* t = g_tus;
  if (blk < 8) {
    int b = blk;
    const float* row = g_bst + b * 4096;
    float mx = -3.4e38f;
    for (int i = tid; i < 4096; i += 256) mx = fmaxf(mx, row[i]);
    sm[tid] = mx; __syncthreads();
    for (int s2 = 128; s2; s2 >>= 1) { if (tid < s2) sm[tid] = fmaxf(sm[tid], sm[tid + s2]); __syncthreads(); }
    mx = sm[0]; __syncthreads();
    float sum = 0.f;
    for (int i = tid; i < 4096; i += 256) {
      float e = __expf(row[i] - mx);
      g_c[b * 4096 + i] = e; sum += e;
    }
    sm[tid] = sum; __syncthreads();
    for (int s2 = 128; s2; s2 >>= 1) { if (tid < s2) sm[tid] += sm[tid + s2]; __syncthreads(); }
    float inv = 1.f / sm[0];
    for (int i = tid; i < 4096; i += 256) g_c[b * 4096 + i] *= inv;
  } else {
    int blk2 = blk - 8;
    int jt = blk2 & 3, dc = blk2 >> 2;
    for (int idx = tid; idx < 1024; idx += 256) {
      int b = idx >> 7, d = idx & 127;
      sm[idx] = g_q[b * 1024 + dc * 128 + d];
    }
    __syncthreads();
    int j = jt * 256 + tid;
    float acc[8] = {0,0,0,0,0,0,0,0};
    for (int dd = 0; dd < 128; ++dd) {
      int d = dc * 128 + dd;
      float mv = g_M[(size_t)d * 1024 + j];
#pragma unroll
      for (int b = 0; b < 8; ++b) acc[b] += sm[(b << 7) + dd] * mv;
    }
#pragma unroll
    for (int b = 0; b < 8; ++b) atomicAdd(&t[b * 1024 + j], acc[b]);
  }
}

// ---- v = t @ W_f^T  (wave per k row of W_f) ---------------------------------
__global__ void kv(const void* __restrict__ Wf)
{
  __shared__ float tl[8192];
  int tid = threadIdx.x;
  int dtf = g_dt[3];
  for (int i = tid; i < 8192; i += 256) tl[i] = g_tus[i];
  __syncthreads();
  int w = tid >> 6, lane = tid & 63;
  int k = blockIdx.x * 4 + w;
  size_t row = (size_t)k * 1024;
  float f[16];
  load8(Wf, row + lane * 8, dtf, f);
  load8(Wf, row + 512 + lane * 8, dtf, f + 8);
  float acc[8];
#pragma unroll
  for (int b = 0; b < 8; ++b) {
    const float* tb = tl + b * 1024;
    float d = 0.f;
#pragma unroll
    for (int j = 0; j < 8; ++j) d += f[j]     * tb[lane * 8 + j];
#pragma unroll
    for (int j = 0; j < 8; ++j) d += f[8 + j] * tb[512 + lane * 8 + j];
    acc[b] = wredsum(d);
  }
  if (lane == 0) {
#pragma unroll
    for (int b = 0; b < 8; ++b) g_v[b * 1024 + k] = acc[b];
  }
}

// ---- THE big pass over feat: delta[b,n] = feat.v ; s[b,k] += c[n]*feat ------
__global__ void __launch_bounds__(256)
kfeat(const void* __restrict__ feat, int need_delta)
{
  __shared__ float sl[4][1024];
  int tid = threadIdx.x, w = tid >> 6, lane = tid & 63;
  int b = blockIdx.x >> 6, ch = blockIdx.x & 63;
  int dtf = g_dt[1];
  float* s = g_tus + 16384;
  float vr[16];
#pragma unroll
  for (int j = 0; j < 16; ++j) vr[j] = 0.f;
  if (need_delta) {
    const float* vb = g_v + b * 1024;
#pragma unroll
    for (int j = 0; j < 8; ++j) { vr[j] = vb[lane * 8 + j]; vr[8 + j] = vb[512 + lane * 8 + j]; }
  }
  float acc[16];
#pragma unroll
  for (int j = 0; j < 16; ++j) acc[j] = 0.f;
  int n0 = ch * 64 + w * 16;
  for (int r = 0; r < 16; ++r) {
    int n = n0 + r;
    size_t row = ((size_t)b * 4096 + n) * 1024;
    float f[16];
    load8(feat, row + lane * 8, dtf, f);
    load8(feat, row + 512 + lane * 8, dtf, f + 8);
    float cn = g_c[b * 4096 + n];
#pragma unroll
    for (int j = 0; j < 16; ++j) acc[j] += cn * f[j];
    if (need_delta) {
      float dot = 0.f;
#pragma unroll
      for (int j = 0; j < 16; ++j) dot += f[j] * vr[j];
      dot = wredsum(dot);
      if (lane == 0) g_delta[b * 4096 + n] = dot;
    }
  }
#pragma unroll
  for (int j = 0; j < 8; ++j) {
    sl[w][lane * 8 + j] = acc[j];
    sl[w][512 + lane * 8 + j] = acc[8 + j];
  }
  __syncthreads();
#pragma unroll
  for (int j = 0; j < 4; ++j) {
    int k = tid * 4 + j;
    float val = sl[0][k] + sl[1][k] + sl[2][k] + sl[3][k];
    atomicAdd(&s[b * 1024 + k], val);
  }
}

// ---- delta stats + b update (blk<8 if do_stats) | u = s @ W_f (rest) --------
__global__ void kpost(const void* __restrict__ Wf, int do_stats)
{
  __shared__ float sm[1024];
  int blk = blockIdx.x, tid = threadIdx.x;
  float* u = g_tus + 8192;
  float* s = g_tus + 16384;
  if (do_stats && blk < 8) {
    int b = blk;
    const float* row = g_delta + b * 4096;
    float xs[16], sum = 0.f, sq = 0.f;
#pragma unroll
    for (int r = 0; r < 16; ++r) { float x = row[tid + 256 * r]; xs[r] = x; sum += x; sq += x * x; }
    sm[tid] = sum; __syncthreads();
    for (int s2 = 128; s2; s2 >>= 1) { if (tid < s2) sm[tid] += sm[tid + s2]; __syncthreads(); }
    sum = sm[0]; __syncthreads();
    sm[tid] = sq; __syncthreads();
    for (int s2 = 128; s2; s2 >>= 1) { if (tid < s2) sm[tid] += sm[tid + s2]; __syncthreads(); }
    sq = sm[0];
    float mean = sum / 4096.f;
    float var = fmaxf((sq - 4096.f * mean * mean) / 4095.f, 0.f);  // ddof=1
    float inv = 1.f / (sqrtf(var) + 1e-9f);
#pragma unroll
    for (int r = 0; r < 16; ++r) {
      int i = tid + 256 * r;
      g_bst[b * 4096 + i] += (xs[r] - mean) * inv;
    }
  } else {
    int dtf = g_dt[3];
    int blk2 = blk - (do_stats ? 8 : 0);
    int jt = blk2 & 3, kc = blk2 >> 2;
    for (int idx = tid; idx < 1024; idx += 256) {
      int b = idx >> 7, kk = idx & 127;
      sm[idx] = s[b * 1024 + kc * 128 + kk];
    }
    __syncthreads();
    int j = jt * 256 + tid;
    float acc[8] = {0,0,0,0,0,0,0,0};
    for (int kk = 0; kk < 128; ++kk) {
      int k = kc * 128 + kk;
      float w = ldf(Wf, (size_t)k * 1024 + j, dtf);
#pragma unroll
      for (int b = 0; b < 8; ++b) acc[b] += sm[(b << 7) + kk] * w;
    }
#pragma unroll
    for (int b = 0; b < 8; ++b) atomicAdd(&u[b * 1024 + j], acc[b]);
  }
}

// ---- out = u @ M^T  (wave per d row of M) -----------------------------------
__global__ void kout()
{
  __shared__ float ul[8192];
  int tid = threadIdx.x;
  for (int i = tid; i < 8192; i += 256) ul[i] = g_tus[8192 + i];
  __syncthreads();
  int w = tid >> 6, lane = tid & 63;
  int d = blockIdx.x * 4 + w;
  const float* row = g_M + (size_t)d * 1024;
  float f[16];
#pragma unroll
  for (int cc = 0; cc < 4; ++cc) {
    float4 x = *(const float4*)(row + cc * 256 + lane * 4);
    f[cc*4+0]=x.x; f[cc*4+1]=x.y; f[cc*4+2]=x.z; f[cc*4+3]=x.w;
  }
  float acc[8];
#pragma unroll
  for (int b = 0; b < 8; ++b) {
    const float* ub = ul + b * 1024;
    float dd = 0.f;
#pragma unroll
    for (int cc = 0; cc < 4; ++cc)
#pragma unroll
      for (int e = 0; e < 4; ++e) dd += f[cc * 4 + e] * ub[cc * 256 + lane * 4 + e];
    acc[b] = wredsum(dd);
  }
  if (lane == 0) {
#pragma unroll
    for (int b = 0; b < 8; ++b) g_outv[b * 1024 + d] = acc[b];
  }
}

// ---- q = LN(q + selu(out*scale)) --------------------------------------------
__global__ void kq(const void* __restrict__ lnw, const void* __restrict__ lnb,
                   float scale)
{
  __shared__ float sm[256];
  int b = blockIdx.x, tid = threadIdx.x;
  int dtw = g_dt[5], dtb = g_dt[6];
  float x[4], sum = 0.f, sq = 0.f;
#pragma unroll
  for (int j = 0; j < 4; ++j) {
    int d = tid * 4 + j;
    float o = g_outv[b * 1024 + d] * scale;
    float se = (o > 0.f) ? SELU_L * o : SELU_L * SELU_A * expm1f(o);
    float val = g_q[b * 1024 + d] + se;
    x[j] = val; sum += val; sq += val * val;
  }
  sm[tid] = sum; __syncthreads();
  for (int s2 = 128; s2; s2 >>= 1) { if (tid < s2) sm[tid] += sm[tid + s2]; __syncthreads(); }
  sum = sm[0]; __syncthreads();
  sm[tid] = sq; __syncthreads();
  for (int s2 = 128; s2; s2 >>= 1) { if (tid < s2) sm[tid] += sm[tid + s2]; __syncthreads(); }
  sq = sm[0];
  float mean = sum / 1024.f;
  float var = fmaxf(sq / 1024.f - mean * mean, 0.f);   // ddof=0
  float rstd = rsqrtf(var + 1e-5f);
#pragma unroll
  for (int j = 0; j < 4; ++j) {
    int d = tid * 4 + j;
    g_q[b * 1024 + d] = (x[j] - mean) * rstd * ldf(lnw, d, dtw) + ldf(lnb, d, dtb);
  }
}

// ---- final: q @ W_out^T + b_out -> F32 output -------------------------------
__global__ void kfin(const void* __restrict__ Wout, const void* __restrict__ bout,
                     float* __restrict__ out)
{
  __shared__ float ql[8192];
  int tid = threadIdx.x;
  int dto = g_dt[7], dtb = g_dt[8];
  for (int i = tid; i < 8192; i += 256) ql[i] = g_q[i];
  __syncthreads();
  int w = tid >> 6, lane = tid & 63;
  int o = blockIdx.x * 4 + w;
  size_t row = (size_t)o * 1024;
  float f[16];
  load8(Wout, row + lane * 8, dto, f);
  load8(Wout, row + 512 + lane * 8, dto, f + 8);
  float acc[8];
#pragma unroll
  for (int b = 0; b < 8; ++b) {
    const float* qb = ql + b * 1024;
    float d = 0.f;
#pragma unroll
    for (int j = 0; j < 8; ++j) d += f[j]     * qb[lane * 8 + j];
#pragma unroll
    for (int j = 0; j < 8; ++j) d += f[8 + j] * qb[512 + lane * 8 + j];
    acc[b] = wredsum(d);
  }
  if (lane == 0) {
    float bo = ldf(bout, o, dtb);
#pragma unroll
    for (int b = 0; b < 8; ++b) out[b * 1024 + o] = acc[b] + bo;
  }
}

extern "C" void kernel_launch(void* const* d_in, const int* in_sizes, int n_in,
                              void* d_out, int out_size, void* d_ws, size_t ws_size,
                              hipStream_t stream)
{
  const void* query = d_in[0];
  const void* feat  = d_in[1];
  const void* Wh    = d_in[2];
  const void* Wf    = d_in[3];
  const void* Wg    = d_in[4];
  const void* lnw   = d_in[5];
  const void* lnb   = d_in[6];
  const void* Wout  = d_in[7];
  const void* bout  = d_in[8];
  const u8*   maskp = (const u8*)d_in[9];
  (void)in_sizes; (void)n_in; (void)out_size; (void)d_ws; (void)ws_size;

  kdet<<<1, 64, 0, stream>>>(query, feat, Wh, Wf, Wg, lnw, lnb, Wout, bout, maskp);
  kprep<<<1060, 256, 0, stream>>>(Wg, Wh, query, maskp);

  for (int i = 0; i < 3; ++i) {
    int nl = (i < 2);  // non-last iteration
    kzero<<<24, 256, 0, stream>>>();                     // zero t,u,s
    ksm<<<8 + (nl ? 32 : 0), 256, 0, stream>>>(nl);
    if (nl) kv<<<256, 256, 0, stream>>>(Wf);
    kfeat<<<512, 256, 0, stream>>>(feat, nl);
    kpost<<<(nl ? 40 : 32), 256, 0, stream>>>(Wf, nl);
    kout<<<256, 256, 0, stream>>>();
    kq<<<8, 256, 0, stream>>>(lnw, lnb, nl ? (1.f / 4096.f) : 1.f);
  }
  kfin<<<256, 256, 0, stream>>>(Wout, bout, (float*)d_out);
}

// Round 6
// 431.722 us; speedup vs baseline: 1.5963x; 1.5963x over previous
//
#include <hip/hip_runtime.h>
#include <hip/hip_bf16.h>

// B=8, N=4096, D=1024, 3 iterations.
// Algebra: fg = (feat @ W_f) @ Wg_mean^T is never materialized.
//   delta[b,n] = feat[b,n,:] . v_b,  v = t @ W_f^T, t = q @ Wg_mean
//   out[b,:]   = u @ Wg_mean^T,      u = s @ W_f,   s[b,k] = sum_n c[b,n] feat[b,n,k]
// Scratch in __device__ globals. Input dtypes sniffed at runtime (r5 counters:
// inputs bf16, output f32 — sniffer kept for robustness, now wave-parallel).
// r5 lesson: never run a deep scalar-load loop on few blocks (latency-bound);
// all small GEMVs are 64-way split-k with fp32 atomics.

using u16 = unsigned short;
using u32 = unsigned int;
using u8  = unsigned char;
using u64 = unsigned long long;

#define SELU_L 1.0507009873554805f
#define SELU_A 1.6732632423543772f

__device__ float g_M[1048576];   // Wg mean (fp32)
__device__ float g_q[8192];      // running q state (zeroed by kdet, q0 via atomics)
__device__ float g_tus[24576];   // t | u | s (zeroed each iteration by kzero)
__device__ float g_bst[32768];   // b logits state
__device__ float g_c[32768];     // softmax
__device__ float g_delta[32768];
__device__ float g_outv[8192];
__device__ float g_v[8192];
__device__ int   g_dt[12];       // 0..8: 0=bf16,1=f32 per float input; [9]=mask mode

__device__ __forceinline__ float blo(u32 u){ return __uint_as_float(u << 16); }
__device__ __forceinline__ float bhi(u32 u){ return __uint_as_float(u & 0xffff0000u); }
__device__ __forceinline__ float b2f(u16 u){ return __uint_as_float(((u32)u) << 16); }

__device__ __forceinline__ void unpack8(uint4 x, float* f){
  f[0]=blo(x.x); f[1]=bhi(x.x); f[2]=blo(x.y); f[3]=bhi(x.y);
  f[4]=blo(x.z); f[5]=bhi(x.z); f[6]=blo(x.w); f[7]=bhi(x.w);
}

__device__ __forceinline__ float ldf(const void* p, size_t i, int dt){
  return dt ? ((const float*)p)[i] : b2f(((const u16*)p)[i]);
}
__device__ __forceinline__ void load8(const void* base, size_t idx, int dt, float* f){
  if (dt == 0) {
    uint4 x = *(const uint4*)((const u16*)base + idx);
    unpack8(x, f);
  } else {
    const float* p = (const float*)base + idx;
    float4 a = *(const float4*)p, b = *(const float4*)(p + 4);
    f[0]=a.x; f[1]=a.y; f[2]=a.z; f[3]=a.w; f[4]=b.x; f[5]=b.y; f[6]=b.z; f[7]=b.w;
  }
}

__device__ __forceinline__ float wredsum(float x){
#pragma unroll
  for (int o = 32; o; o >>= 1) x += __shfl_xor(x, o, 64);
  return x;
}

// ---- dtype sniffer (wave-parallel) + zero g_q -------------------------------
__global__ void kdet(const void* p0, const void* p1, const void* p2, const void* p3,
                     const void* p4, const void* p5, const void* p6, const void* p7,
                     const void* p8, const void* p9)
{
  const void* ps[10] = {p0,p1,p2,p3,p4,p5,p6,p7,p8,p9};
  int tid = threadIdx.x;
  int w = tid >> 6, lane = tid & 63;
  if (w < 9) {
    const u16* wp = (const u16*)ps[w];
    u16 x0 = wp[lane], x1 = wp[64 + lane];
    int e0 = (x0 >> 7) & 0xFF, e1 = (x1 >> 7) & 0xFF;
    u64 nz0 = __ballot(x0 != 0), nz1 = __ballot(x1 != 0);
    u64 pa0 = __ballot(x0 != 0 && e0 >= 0x70 && e0 <= 0x8F);
    u64 pa1 = __ballot(x1 != 0 && e1 >= 0x70 && e1 <= 0x8F);
    if (lane == 0) {
      const u64 evenm = 0x5555555555555555ULL;   // i parity == lane parity
      int nz = __popcll(nz0) + __popcll(nz1);
      int pass = __popcll(pa0) + __popcll(pa1);
      int evenNZ = __popcll(nz0 & evenm) + __popcll(nz1 & evenm);
      int oddNZ  = nz - evenNZ;
      int dt;
      if (nz == 0)                    dt = 0;
      else if (evenNZ == 0 && oddNZ)  dt = 1;    // f32 signature
      else                            dt = (pass * 10 >= nz * 9) ? 0 : 1;
      g_dt[w] = dt;
    }
  } else if (w == 9) {
    const u8* mp = (const u8*)ps[9];
    u64 v = ((const u64*)mp)[lane];              // bytes lane*8 .. lane*8+7
    bool f16c=false, isF=false, nz01=false, nzNon4=false, nzM8_4=false, anynz=false;
#pragma unroll
    for (int j = 0; j < 8; ++j) {
      u8 cb = (u8)(v >> (8 * j));
      if (!cb) continue;
      int i = lane * 8 + j;
      anynz = true;
      if (cb == 0x3C && (i & 1)) f16c = true;
      if (cb == 0x3F || cb == 0x80) isF = true;
      int m = i & 3;
      if (m == 0 || m == 1) nz01 = true;
      if (m != 0) nzNon4 = true;
      if ((i & 7) == 4) nzM8_4 = true;
    }
    bool A  = __ballot(f16c)   != 0;
    bool Bf = __ballot(isF)    != 0;
    bool C  = __ballot(nz01)   != 0;
    bool Dn = __ballot(nzNon4) != 0;
    bool E  = __ballot(nzM8_4) != 0;
    bool F  = __ballot(anynz)  != 0;
    if (lane == 0) {
      int mode;
      if (A)       mode = 4;                     // f16
      else if (Bf) mode = C ? 2 : 3;             // bf16 : f32
      else if (Dn) mode = 0;                     // u8
      else if (E)  mode = 1;                     // i32
      else if (F)  mode = 5;                     // i64
      else         mode = 1;
      g_dt[9] = mode;
    }
  }
  for (int i = tid; i < 8192; i += 640) g_q[i] = 0.f;
}

__global__ void kzero() {
  int i = (blockIdx.x * 256 + threadIdx.x) * 4;
  *(float4*)(g_tus + i) = make_float4(0.f, 0.f, 0.f, 0.f);
}

// ---- prep: M (blk<1024) | q0 split-64 (blk<1088) | mask (blk<1120) ----------
__global__ void kprep(const void* __restrict__ Wg, const void* __restrict__ Wh,
                      const void* __restrict__ query, const u8* __restrict__ maskp)
{
  int blk = blockIdx.x, tid = threadIdx.x;
  if (blk < 1024) {
    int dtg = g_dt[4];
    int e = blk * 1024 + tid * 4;
    float a0=0.f,a1=0.f,a2=0.f,a3=0.f;
#pragma unroll
    for (int g = 0; g < 4; ++g) {
      size_t o = (size_t)g * 1048576 + e;
      a0 += ldf(Wg, o+0, dtg); a1 += ldf(Wg, o+1, dtg);
      a2 += ldf(Wg, o+2, dtg); a3 += ldf(Wg, o+3, dtg);
    }
    *(float4*)(g_M + e) = make_float4(a0*0.25f, a1*0.25f, a2*0.25f, a3*0.25f);
  } else if (blk < 1088) {
    // q0[b,k] += sum_{d in chunk} query[b,d] * Wh[d,k]; 4 k-tiles x 16 d-chunks
    int dtq = g_dt[0], dth = g_dt[2];
    __shared__ float ql[512];                    // [b][64]
    int blk2 = blk - 1024;
    int kt = blk2 & 3, dc = blk2 >> 2;
    for (int idx = tid; idx < 512; idx += 256) {
      int b = idx >> 6, d = idx & 63;
      ql[idx] = ldf(query, b * 1024 + dc * 64 + d, dtq);
    }
    __syncthreads();
    int k = kt * 256 + tid;
    float acc[8] = {0,0,0,0,0,0,0,0};
    for (int dd = 0; dd < 64; ++dd) {
      int d = dc * 64 + dd;
      float w = ldf(Wh, (size_t)d * 1024 + k, dth);
#pragma unroll
      for (int b = 0; b < 8; ++b) acc[b] += ql[(b << 6) + dd] * w;
    }
#pragma unroll
    for (int b = 0; b < 8; ++b) atomicAdd(&g_q[b * 1024 + k], acc[b]);
  } else {
    int mode = g_dt[9];
    int e0 = (blk - 1088) * 1024 + tid * 4;
#pragma unroll
    for (int j = 0; j < 4; ++j) {
      int e = e0 + j;
      bool on;
      if (mode == 0)      on = maskp[e] != 0;
      else if (mode == 1) on = ((const int*)maskp)[e] != 0;
      else if (mode == 2) on = ((const u16*)maskp)[e] != 0;
      else if (mode == 3) on = ((const u32*)maskp)[e] != 0;
      else if (mode == 4) on = ((const u16*)maskp)[e] != 0;
      else                on = ((const u64*)maskp)[e] != 0ULL;
      g_bst[e] = on ? -1e18f : 0.f;
    }
  }
}

// ---- softmax(bst)->c (blk<8) | t = q @ M split-64 (blk 8..71) ---------------
__global__ void ksm(int do_t)
{
  __shared__ float sm[1024];
  int blk = blockIdx.x, tid = threadIdx.x;
  float* t = g_tus;
  if (blk < 8) {
    int b = blk;
    const float* row = g_bst + b * 4096;
    float mx = -3.4e38f;
    for (int i = tid; i < 4096; i += 256) mx = fmaxf(mx, row[i]);
    sm[tid] = mx; __syncthreads();
    for (int s2 = 128; s2; s2 >>= 1) { if (tid < s2) sm[tid] = fmaxf(sm[tid], sm[tid + s2]); __syncthreads(); }
    mx = sm[0]; __syncthreads();
    float sum = 0.f;
    for (int i = tid; i < 4096; i += 256) {
      float e = __expf(row[i] - mx);
      g_c[b * 4096 + i] = e; sum += e;
    }
    sm[tid] = sum; __syncthreads();
    for (int s2 = 128; s2; s2 >>= 1) { if (tid < s2) sm[tid] += sm[tid + s2]; __syncthreads(); }
    float inv = 1.f / sm[0];
    for (int i = tid; i < 4096; i += 256) g_c[b * 4096 + i] *= inv;
  } else {
    int blk2 = blk - 8;
    int jt = blk2 & 3, dc = blk2 >> 2;           // dc in [0,16)
    for (int idx = tid; idx < 512; idx += 256) {
      int b = idx >> 6, d = idx & 63;
      sm[idx] = g_q[b * 1024 + dc * 64 + d];
    }
    __syncthreads();
    int j = jt * 256 + tid;
    float acc[8] = {0,0,0,0,0,0,0,0};
    for (int dd = 0; dd < 64; ++dd) {
      int d = dc * 64 + dd;
      float mv = g_M[(size_t)d * 1024 + j];
#pragma unroll
      for (int b = 0; b < 8; ++b) acc[b] += sm[(b << 6) + dd] * mv;
    }
#pragma unroll
    for (int b = 0; b < 8; ++b) atomicAdd(&t[b * 1024 + j], acc[b]);
  }
}

// ---- v = t @ W_f^T  (wave per k row of W_f) ---------------------------------
__global__ void kv(const void* __restrict__ Wf)
{
  __shared__ float tl[8192];
  int tid = threadIdx.x;
  int dtf = g_dt[3];
  for (int i = tid; i < 8192; i += 256) tl[i] = g_tus[i];
  __syncthreads();
  int w = tid >> 6, lane = tid & 63;
  int k = blockIdx.x * 4 + w;
  size_t row = (size_t)k * 1024;
  float f[16];
  load8(Wf, row + lane * 8, dtf, f);
  load8(Wf, row + 512 + lane * 8, dtf, f + 8);
  float acc[8];
#pragma unroll
  for (int b = 0; b < 8; ++b) {
    const float* tb = tl + b * 1024;
    float d = 0.f;
#pragma unroll
    for (int j = 0; j < 8; ++j) d += f[j]     * tb[lane * 8 + j];
#pragma unroll
    for (int j = 0; j < 8; ++j) d += f[8 + j] * tb[512 + lane * 8 + j];
    acc[b] = wredsum(d);
  }
  if (lane == 0) {
#pragma unroll
    for (int b = 0; b < 8; ++b) g_v[b * 1024 + k] = acc[b];
  }
}

// ---- THE big pass over feat: delta[b,n] = feat.v ; s[b,k] += c[n]*feat ------
__global__ void __launch_bounds__(256)
kfeat(const void* __restrict__ feat, int need_delta)
{
  __shared__ float sl[4][1024];
  int tid = threadIdx.x, w = tid >> 6, lane = tid & 63;
  int b = blockIdx.x >> 6, ch = blockIdx.x & 63;
  int dtf = g_dt[1];
  float* s = g_tus + 16384;
  float vr[16];
#pragma unroll
  for (int j = 0; j < 16; ++j) vr[j] = 0.f;
  if (need_delta) {
    const float* vb = g_v + b * 1024;
#pragma unroll
    for (int j = 0; j < 8; ++j) { vr[j] = vb[lane * 8 + j]; vr[8 + j] = vb[512 + lane * 8 + j]; }
  }
  float acc[16];
#pragma unroll
  for (int j = 0; j < 16; ++j) acc[j] = 0.f;
  int n0 = ch * 64 + w * 16;
  for (int r = 0; r < 16; ++r) {
    int n = n0 + r;
    size_t row = ((size_t)b * 4096 + n) * 1024;
    float f[16];
    load8(feat, row + lane * 8, dtf, f);
    load8(feat, row + 512 + lane * 8, dtf, f + 8);
    float cn = g_c[b * 4096 + n];
#pragma unroll
    for (int j = 0; j < 16; ++j) acc[j] += cn * f[j];
    if (need_delta) {
      float dot = 0.f;
#pragma unroll
      for (int j = 0; j < 16; ++j) dot += f[j] * vr[j];
      dot = wredsum(dot);
      if (lane == 0) g_delta[b * 4096 + n] = dot;
    }
  }
#pragma unroll
  for (int j = 0; j < 8; ++j) {
    sl[w][lane * 8 + j] = acc[j];
    sl[w][512 + lane * 8 + j] = acc[8 + j];
  }
  __syncthreads();
#pragma unroll
  for (int j = 0; j < 4; ++j) {
    int k = tid * 4 + j;
    float val = sl[0][k] + sl[1][k] + sl[2][k] + sl[3][k];
    atomicAdd(&s[b * 1024 + k], val);
  }
}

// ---- delta stats (blk<8 if do_stats) | u = s @ W_f split-64 (rest) ----------
__global__ void kpost(const void* __restrict__ Wf, int do_stats)
{
  __shared__ float sm[1024];
  int blk = blockIdx.x, tid = threadIdx.x;
  float* u = g_tus + 8192;
  float* s = g_tus + 16384;
  if (do_stats && blk < 8) {
    int b = blk;
    const float* row = g_delta + b * 4096;
    float xs[16], sum = 0.f, sq = 0.f;
#pragma unroll
    for (int r = 0; r < 16; ++r) { float x = row[tid + 256 * r]; xs[r] = x; sum += x; sq += x * x; }
    sm[tid] = sum; __syncthreads();
    for (int s2 = 128; s2; s2 >>= 1) { if (tid < s2) sm[tid] += sm[tid + s2]; __syncthreads(); }
    sum = sm[0]; __syncthreads();
    sm[tid] = sq; __syncthreads();
    for (int s2 = 128; s2; s2 >>= 1) { if (tid < s2) sm[tid] += sm[tid + s2]; __syncthreads(); }
    sq = sm[0];
    float mean = sum / 4096.f;
    float var = fmaxf((sq - 4096.f * mean * mean) / 4095.f, 0.f);  // ddof=1
    float inv = 1.f / (sqrtf(var) + 1e-9f);
#pragma unroll
    for (int r = 0; r < 16; ++r) {
      int i = tid + 256 * r;
      g_bst[b * 4096 + i] += (xs[r] - mean) * inv;
    }
  } else {
    int dtf = g_dt[3];
    int blk2 = blk - (do_stats ? 8 : 0);
    int jt = blk2 & 3, kc = blk2 >> 2;           // kc in [0,16)
    for (int idx = tid; idx < 512; idx += 256) {
      int b = idx >> 6, kk = idx & 63;
      sm[idx] = s[b * 1024 + kc * 64 + kk];
    }
    __syncthreads();
    int j = jt * 256 + tid;
    float acc[8] = {0,0,0,0,0,0,0,0};
    for (int kk = 0; kk < 64; ++kk) {
      int k = kc * 64 + kk;
      float w = ldf(Wf, (size_t)k * 1024 + j, dtf);
#pragma unroll
      for (int b = 0; b < 8; ++b) acc[b] += sm[(b << 6) + kk] * w;
    }
#pragma unroll
    for (int b = 0; b < 8; ++b) atomicAdd(&u[b * 1024 + j], acc[b]);
  }
}

// ---- out = u @ M^T  (wave per d row of M) -----------------------------------
__global__ void kout()
{
  __shared__ float ul[8192];
  int tid = threadIdx.x;
  for (int i = tid; i < 8192; i += 256) ul[i] = g_tus[8192 + i];
  __syncthreads();
  int w = tid >> 6, lane = tid & 63;
  int d = blockIdx.x * 4 + w;
  const float* row = g_M + (size_t)d * 1024;
  float f[16];
#pragma unroll
  for (int cc = 0; cc < 4; ++cc) {
    float4 x = *(const float4*)(row + cc * 256 + lane * 4);
    f[cc*4+0]=x.x; f[cc*4+1]=x.y; f[cc*4+2]=x.z; f[cc*4+3]=x.w;
  }
  float acc[8];
#pragma unroll
  for (int b = 0; b < 8; ++b) {
    const float* ub = ul + b * 1024;
    float dd = 0.f;
#pragma unroll
    for (int cc = 0; cc < 4; ++cc)
#pragma unroll
      for (int e = 0; e < 4; ++e) dd += f[cc * 4 + e] * ub[cc * 256 + lane * 4 + e];
    acc[b] = wredsum(dd);
  }
  if (lane == 0) {
#pragma unroll
    for (int b = 0; b < 8; ++b) g_outv[b * 1024 + d] = acc[b];
  }
}

// ---- q = LN(q + selu(out*scale)) --------------------------------------------
__global__ void kq(const void* __restrict__ lnw, const void* __restrict__ lnb,
                   float scale)
{
  __shared__ float sm[256];
  int b = blockIdx.x, tid = threadIdx.x;
  int dtw = g_dt[5], dtb = g_dt[6];
  float x[4], sum = 0.f, sq = 0.f;
#pragma unroll
  for (int j = 0; j < 4; ++j) {
    int d = tid * 4 + j;
    float o = g_outv[b * 1024 + d] * scale;
    float se = (o > 0.f) ? SELU_L * o : SELU_L * SELU_A * expm1f(o);
    float val = g_q[b * 1024 + d] + se;
    x[j] = val; sum += val; sq += val * val;
  }
  sm[tid] = sum; __syncthreads();
  for (int s2 = 128; s2; s2 >>= 1) { if (tid < s2) sm[tid] += sm[tid + s2]; __syncthreads(); }
  sum = sm[0]; __syncthreads();
  sm[tid] = sq; __syncthreads();
  for (int s2 = 128; s2; s2 >>= 1) { if (tid < s2) sm[tid] += sm[tid + s2]; __syncthreads(); }
  sq = sm[0];
  float mean = sum / 1024.f;
  float var = fmaxf(sq / 1024.f - mean * mean, 0.f);   // ddof=0
  float rstd = rsqrtf(var + 1e-5f);
#pragma unroll
  for (int j = 0; j < 4; ++j) {
    int d = tid * 4 + j;
    g_q[b * 1024 + d] = (x[j] - mean) * rstd * ldf(lnw, d, dtw) + ldf(lnb, d, dtb);
  }
}

// ---- final: q @ W_out^T + b_out -> F32 output -------------------------------
__global__ void kfin(const void* __restrict__ Wout, const void* __restrict__ bout,
                     float* __restrict__ out)
{
  __shared__ float ql[8192];
  int tid = threadIdx.x;
  int dto = g_dt[7], dtb = g_dt[8];
  for (int i = tid; i < 8192; i += 256) ql[i] = g_q[i];
  __syncthreads();
  int w = tid >> 6, lane = tid & 63;
  int o = blockIdx.x * 4 + w;
  size_t row = (size_t)o * 1024;
  float f[16];
  load8(Wout, row + lane * 8, dto, f);
  load8(Wout, row + 512 + lane * 8, dto, f + 8);
  float acc[8];
#pragma unroll
  for (int b = 0; b < 8; ++b) {
    const float* qb = ql + b * 1024;
    float d = 0.f;
#pragma unroll
    for (int j = 0; j < 8; ++j) d += f[j]     * qb[lane * 8 + j];
#pragma unroll
    for (int j = 0; j < 8; ++j) d += f[8 + j] * qb[512 + lane * 8 + j];
    acc[b] = wredsum(d);
  }
  if (lane == 0) {
    float bo = ldf(bout, o, dtb);
#pragma unroll
    for (int b = 0; b < 8; ++b) out[b * 1024 + o] = acc[b] + bo;
  }
}

extern "C" void kernel_launch(void* const* d_in, const int* in_sizes, int n_in,
                              void* d_out, int out_size, void* d_ws, size_t ws_size,
                              hipStream_t stream)
{
  const void* query = d_in[0];
  const void* feat  = d_in[1];
  const void* Wh    = d_in[2];
  const void* Wf    = d_in[3];
  const void* Wg    = d_in[4];
  const void* lnw   = d_in[5];
  const void* lnb   = d_in[6];
  const void* Wout  = d_in[7];
  const void* bout  = d_in[8];
  const u8*   maskp = (const u8*)d_in[9];
  (void)in_sizes; (void)n_in; (void)out_size; (void)d_ws; (void)ws_size;

  kdet<<<1, 640, 0, stream>>>(query, feat, Wh, Wf, Wg, lnw, lnb, Wout, bout, maskp);
  kprep<<<1120, 256, 0, stream>>>(Wg, Wh, query, maskp);

  for (int i = 0; i < 3; ++i) {
    int nl = (i < 2);  // non-last iteration
    kzero<<<24, 256, 0, stream>>>();                     // zero t,u,s
    ksm<<<8 + (nl ? 64 : 0), 256, 0, stream>>>(nl);
    if (nl) kv<<<256, 256, 0, stream>>>(Wf);
    kfeat<<<512, 256, 0, stream>>>(feat, nl);
    kpost<<<(nl ? 8 : 0) + 64, 256, 0, stream>>>(Wf, nl);
    kout<<<256, 256, 0, stream>>>();
    kq<<<8, 256, 0, stream>>>(lnw, lnb, nl ? (1.f / 4096.f) : 1.f);
  }
  kfin<<<256, 256, 0, stream>>>(Wout, bout, (float*)d_out);
}